// Round 1
// baseline (800.743 us; speedup 1.0000x reference)
//
#include <hip/hip_runtime.h>

#define N_NODES 50000
#define N_EDGES 800000
#define D 128

// ---------------------------------------------------------------------------
// Phase 1: support = inputs @ weight   (fp32, vector ALU — no fp32 MFMA on CDNA4)
// Block = 256 threads, 32 rows per block. W (64KB) fully in LDS; 32 input rows
// staged transposed (inT[k][r], pad 36) so the inner loop is 2x ds_read_b128
// (one broadcast, one contiguous) feeding 16 independent FMAs.
// ---------------------------------------------------------------------------
__global__ __launch_bounds__(256) void gemm_kernel(
    const float* __restrict__ inp, const float* __restrict__ W,
    float* __restrict__ support, int n)
{
    __shared__ float Ws[128][128];   // 64 KB
    __shared__ float inT[128][36];   // 18 KB, padded: conflict-free transpose writes
    const int tid = threadIdx.x;

    // Load W into LDS: 1024 float4 / 256 threads = 4 each... (16384 floats)
    {
        const float4* Wg = (const float4*)W;
        float4* Wl = (float4*)&Ws[0][0];
        #pragma unroll
        for (int i = 0; i < 16; ++i) Wl[tid + 256 * i] = Wg[tid + 256 * i];
    }

    const int row0 = blockIdx.x * 32;
    // Stage 32 rows of inputs, transposed. idx -> (r = idx&31, c4 = idx>>5)
    #pragma unroll
    for (int i = 0; i < 4; ++i) {
        int idx = tid + 256 * i;
        int r = idx & 31;
        int c4 = idx >> 5;   // 0..31 (float4 column group)
        float4 v = make_float4(0.f, 0.f, 0.f, 0.f);
        if (row0 + r < n) v = *(const float4*)&inp[(size_t)(row0 + r) * D + c4 * 4];
        inT[c4 * 4 + 0][r] = v.x;
        inT[c4 * 4 + 1][r] = v.y;
        inT[c4 * 4 + 2][r] = v.z;
        inT[c4 * 4 + 3][r] = v.w;
    }
    __syncthreads();

    const int c0 = (tid & 31) * 4;   // output column
    const int r0 = (tid >> 5) * 4;   // output row (within the 32-row tile)
    float acc[4][4] = {};

    #pragma unroll 8
    for (int k = 0; k < 128; ++k) {
        float4 w = *(const float4*)&Ws[k][c0];
        float4 a = *(const float4*)&inT[k][r0];
        acc[0][0] += a.x * w.x; acc[0][1] += a.x * w.y; acc[0][2] += a.x * w.z; acc[0][3] += a.x * w.w;
        acc[1][0] += a.y * w.x; acc[1][1] += a.y * w.y; acc[1][2] += a.y * w.z; acc[1][3] += a.y * w.w;
        acc[2][0] += a.z * w.x; acc[2][1] += a.z * w.y; acc[2][2] += a.z * w.z; acc[2][3] += a.z * w.w;
        acc[3][0] += a.w * w.x; acc[3][1] += a.w * w.y; acc[3][2] += a.w * w.z; acc[3][3] += a.w * w.w;
    }

    #pragma unroll
    for (int i = 0; i < 4; ++i) {
        int r = row0 + r0 + i;
        if (r < n) {
            float4 o = make_float4(acc[i][0], acc[i][1], acc[i][2], acc[i][3]);
            *(float4*)&support[(size_t)r * D + c0] = o;
        }
    }
}

// ---------------------------------------------------------------------------
// Phase 2: COO SpMM scatter: agg[row] += val * support[col]
// One wave (64 lanes) per edge; lane handles 2 columns (float2 gather,
// 2 x atomicAdd). Edge metadata is wave-uniform.
// ---------------------------------------------------------------------------
__global__ __launch_bounds__(256) void spmm_scatter(
    const float* __restrict__ support, const float* __restrict__ vals,
    const int* __restrict__ rows, const int* __restrict__ cols,
    float* __restrict__ agg)
{
    const int wave = (blockIdx.x * blockDim.x + threadIdx.x) >> 6;
    const int lane = threadIdx.x & 63;
    if (wave >= N_EDGES) return;

    const float v = vals[wave];
    const int c = cols[wave];
    const int r = rows[wave];

    const float2 s = *(const float2*)&support[(size_t)c * D + lane * 2];
    float* dst = &agg[(size_t)r * D + lane * 2];
    atomicAdd(dst + 0, s.x * v);
    atomicAdd(dst + 1, s.y * v);
}

// ---------------------------------------------------------------------------
// Phase 3: out = elu(agg*g0 + inputs*g1 + bias), in-place on d_out (agg)
// ---------------------------------------------------------------------------
__global__ __launch_bounds__(256) void combine_kernel(
    float* __restrict__ out, const float* __restrict__ inp,
    const float* __restrict__ bias, const float* __restrict__ alpha, int total4)
{
    // softmax gate over alpha[0], alpha[1]
    const float a0 = alpha[0], a1 = alpha[1];
    const float m = fmaxf(a0, a1);
    const float e0 = __expf(a0 - m), e1 = __expf(a1 - m);
    const float inv = 1.f / (e0 + e1);
    const float g0 = e0 * inv, g1 = e1 * inv;

    const int stride = gridDim.x * blockDim.x;
    for (int i = blockIdx.x * blockDim.x + threadIdx.x; i < total4; i += stride) {
        float4 agg = ((const float4*)out)[i];
        float4 x   = ((const float4*)inp)[i];
        float4 b   = ((const float4*)bias)[i & 31];   // 128 cols = 32 float4
        float t0 = agg.x * g0 + x.x * g1 + b.x;
        float t1 = agg.y * g0 + x.y * g1 + b.y;
        float t2 = agg.z * g0 + x.z * g1 + b.z;
        float t3 = agg.w * g0 + x.w * g1 + b.w;
        float4 o;
        o.x = t0 > 0.f ? t0 : (__expf(t0) - 1.f);
        o.y = t1 > 0.f ? t1 : (__expf(t1) - 1.f);
        o.z = t2 > 0.f ? t2 : (__expf(t2) - 1.f);
        o.w = t3 > 0.f ? t3 : (__expf(t3) - 1.f);
        ((float4*)out)[i] = o;
    }
}

extern "C" void kernel_launch(void* const* d_in, const int* in_sizes, int n_in,
                              void* d_out, int out_size, void* d_ws, size_t ws_size,
                              hipStream_t stream)
{
    const float* inp   = (const float*)d_in[0];
    const float* W     = (const float*)d_in[1];
    const float* bias  = (const float*)d_in[2];
    const float* alpha = (const float*)d_in[3];
    const float* vals  = (const float*)d_in[4];
    const int*   rows  = (const int*)d_in[5];
    const int*   cols  = (const int*)d_in[6];

    float* out = (float*)d_out;                  // agg accumulates here, fixed up in-place
    float* support = (float*)d_ws;               // [N_NODES * D] fp32 = 25.6 MB

    // zero the accumulator (graph-capture-legal memset node)
    hipMemsetAsync(out, 0, (size_t)out_size * sizeof(float), stream);

    gemm_kernel<<<(N_NODES + 31) / 32, 256, 0, stream>>>(inp, W, support, N_NODES);
    spmm_scatter<<<(N_EDGES + 3) / 4, 256, 0, stream>>>(support, vals, rows, cols, out);
    combine_kernel<<<2048, 256, 0, stream>>>(out, inp, bias, alpha, (N_NODES * D) / 4);
}

// Round 2
// 275.406 us; speedup vs baseline: 2.9075x; 2.9075x over previous
//
#include <hip/hip_runtime.h>

#define N_NODES 50000
#define N_EDGES 800000
#define D 128

// ---------------------------------------------------------------------------
// Phase 1: support = inputs @ weight (fp32 vector GEMM, k-tiled: 42KB LDS ->
// 3 blocks/CU -> 3 waves/SIMD for latency hiding; was 82KB -> 1 wave/SIMD)
// ---------------------------------------------------------------------------
__global__ __launch_bounds__(256) void gemm_kernel(
    const float* __restrict__ inp, const float* __restrict__ W,
    float* __restrict__ support, int n)
{
    __shared__ float Ws[64][128];   // 32 KB (k-slice of W)
    __shared__ float inT[64][36];   // 9 KB padded transpose
    const int tid = threadIdx.x;
    const int row0 = blockIdx.x * 32;
    const int c0 = (tid & 31) * 4;   // output column
    const int r0 = (tid >> 5) * 4;   // output row within tile
    float acc[4][4] = {};

    for (int kp = 0; kp < 128; kp += 64) {
        // stage W k-slice: 8192 floats = 2048 float4 / 256 threads
        const float4* Wg = (const float4*)(W + kp * 128);
        float4* Wl = (float4*)&Ws[0][0];
        #pragma unroll
        for (int i = 0; i < 8; ++i) Wl[tid + 256 * i] = Wg[tid + 256 * i];
        // stage 32 input rows x 64 k, transposed: 512 float4 / 256 threads
        #pragma unroll
        for (int i = 0; i < 2; ++i) {
            int idx = tid + 256 * i;     // 0..511
            int r = idx & 31;
            int c4 = idx >> 5;           // 0..15
            float4 v = make_float4(0.f, 0.f, 0.f, 0.f);
            if (row0 + r < n) v = *(const float4*)&inp[(size_t)(row0 + r) * D + kp + c4 * 4];
            inT[c4 * 4 + 0][r] = v.x;
            inT[c4 * 4 + 1][r] = v.y;
            inT[c4 * 4 + 2][r] = v.z;
            inT[c4 * 4 + 3][r] = v.w;
        }
        __syncthreads();

        #pragma unroll 8
        for (int k = 0; k < 64; ++k) {
            float4 w = *(const float4*)&Ws[k][c0];
            float4 a = *(const float4*)&inT[k][r0];
            acc[0][0] += a.x * w.x; acc[0][1] += a.x * w.y; acc[0][2] += a.x * w.z; acc[0][3] += a.x * w.w;
            acc[1][0] += a.y * w.x; acc[1][1] += a.y * w.y; acc[1][2] += a.y * w.z; acc[1][3] += a.y * w.w;
            acc[2][0] += a.z * w.x; acc[2][1] += a.z * w.y; acc[2][2] += a.z * w.z; acc[2][3] += a.z * w.w;
            acc[3][0] += a.w * w.x; acc[3][1] += a.w * w.y; acc[3][2] += a.w * w.z; acc[3][3] += a.w * w.w;
        }
        __syncthreads();
    }

    #pragma unroll
    for (int i = 0; i < 4; ++i) {
        int r = row0 + r0 + i;
        if (r < n)
            *(float4*)&support[(size_t)r * D + c0] =
                make_float4(acc[i][0], acc[i][1], acc[i][2], acc[i][3]);
    }
}

// ---------------------------------------------------------------------------
// Phase 2a: histogram of destination rows
// ---------------------------------------------------------------------------
__global__ __launch_bounds__(256) void hist_kernel(const int* __restrict__ rows,
                                                   int* __restrict__ counts)
{
    int e = blockIdx.x * 256 + threadIdx.x;
    if (e < N_EDGES) atomicAdd(&counts[rows[e]], 1);
}

// ---------------------------------------------------------------------------
// Phase 2b: 3-kernel exclusive scan of counts -> offsets (+ cursor copy)
// ---------------------------------------------------------------------------
__global__ __launch_bounds__(256) void scan1(const int* __restrict__ counts,
                                             int* __restrict__ offsets,
                                             int* __restrict__ blockSums)
{
    __shared__ int s[256];
    int gid = blockIdx.x * 256 + threadIdx.x;
    int v = (gid < N_NODES) ? counts[gid] : 0;
    s[threadIdx.x] = v;
    __syncthreads();
    #pragma unroll
    for (int d = 1; d < 256; d <<= 1) {
        int t = (threadIdx.x >= d) ? s[threadIdx.x - d] : 0;
        __syncthreads();
        s[threadIdx.x] += t;
        __syncthreads();
    }
    if (gid < N_NODES) offsets[gid] = s[threadIdx.x] - v;   // exclusive, local
    if (threadIdx.x == 255) blockSums[blockIdx.x] = s[255]; // block total
}

__global__ __launch_bounds__(256) void scan2(int* __restrict__ blockSums, int nb)
{
    __shared__ int s[256];
    int v = (threadIdx.x < nb) ? blockSums[threadIdx.x] : 0;
    s[threadIdx.x] = v;
    __syncthreads();
    #pragma unroll
    for (int d = 1; d < 256; d <<= 1) {
        int t = (threadIdx.x >= d) ? s[threadIdx.x - d] : 0;
        __syncthreads();
        s[threadIdx.x] += t;
        __syncthreads();
    }
    if (threadIdx.x < nb) blockSums[threadIdx.x] = s[threadIdx.x] - v; // exclusive
}

__global__ __launch_bounds__(256) void scan3(int* __restrict__ offsets,
                                             int* __restrict__ cursor,
                                             const int* __restrict__ blockSums)
{
    int gid = blockIdx.x * 256 + threadIdx.x;
    if (gid < N_NODES) {
        int o = offsets[gid] + blockSums[blockIdx.x];
        offsets[gid] = o;
        cursor[gid] = o;
    }
    if (gid == 0) offsets[N_NODES] = N_EDGES;
}

// ---------------------------------------------------------------------------
// Phase 2c: scatter edges into CSR order
// ---------------------------------------------------------------------------
__global__ __launch_bounds__(256) void scatter_kernel(
    const int* __restrict__ rows, const int* __restrict__ cols,
    const float* __restrict__ vals, int* __restrict__ cursor,
    int* __restrict__ sc, float* __restrict__ sv)
{
    int e = blockIdx.x * 256 + threadIdx.x;
    if (e < N_EDGES) {
        int p = atomicAdd(&cursor[rows[e]], 1);
        sc[p] = cols[e];
        sv[p] = vals[e];
    }
}

// ---------------------------------------------------------------------------
// Phase 3: per-row gather-reduce + fused softmax-gate/bias/ELU epilogue.
// One wave per destination row; lane owns 2 columns (float2). No atomics,
// each output element written exactly once.
// ---------------------------------------------------------------------------
__global__ __launch_bounds__(256) void agg_fused(
    const float* __restrict__ support, const int* __restrict__ offsets,
    const int* __restrict__ sc, const float* __restrict__ sv,
    const float* __restrict__ inp, const float* __restrict__ bias,
    const float* __restrict__ alpha, float* __restrict__ out)
{
    const int wave = (blockIdx.x * 256 + threadIdx.x) >> 6;
    const int lane = threadIdx.x & 63;
    if (wave >= N_NODES) return;

    const int start = offsets[wave];
    const int end   = offsets[wave + 1];

    float2 acc = make_float2(0.f, 0.f);
    int e = start;
    for (; e + 1 < end; e += 2) {        // 2-way unroll: independent gathers
        int   c0 = sc[e],     c1 = sc[e + 1];
        float v0 = sv[e],     v1 = sv[e + 1];
        float2 s0 = *(const float2*)&support[(size_t)c0 * D + lane * 2];
        float2 s1 = *(const float2*)&support[(size_t)c1 * D + lane * 2];
        acc.x += v0 * s0.x + v1 * s1.x;
        acc.y += v0 * s0.y + v1 * s1.y;
    }
    if (e < end) {
        int c = sc[e]; float v = sv[e];
        float2 s = *(const float2*)&support[(size_t)c * D + lane * 2];
        acc.x += v * s.x;
        acc.y += v * s.y;
    }

    // softmax gate over alpha[0..1]
    const float a0 = alpha[0], a1 = alpha[1];
    const float m = fmaxf(a0, a1);
    const float e0 = __expf(a0 - m), e1 = __expf(a1 - m);
    const float inv = 1.f / (e0 + e1);
    const float g0 = e0 * inv, g1 = e1 * inv;

    const float2 x = *(const float2*)&inp[(size_t)wave * D + lane * 2];
    const float2 b = *(const float2*)&bias[lane * 2];
    float t0 = acc.x * g0 + x.x * g1 + b.x;
    float t1 = acc.y * g0 + x.y * g1 + b.y;
    float2 o;
    o.x = t0 > 0.f ? t0 : (__expf(t0) - 1.f);
    o.y = t1 > 0.f ? t1 : (__expf(t1) - 1.f);
    *(float2*)&out[(size_t)wave * D + lane * 2] = o;
}

extern "C" void kernel_launch(void* const* d_in, const int* in_sizes, int n_in,
                              void* d_out, int out_size, void* d_ws, size_t ws_size,
                              hipStream_t stream)
{
    const float* inp   = (const float*)d_in[0];
    const float* W     = (const float*)d_in[1];
    const float* bias  = (const float*)d_in[2];
    const float* alpha = (const float*)d_in[3];
    const float* vals  = (const float*)d_in[4];
    const int*   rows  = (const int*)d_in[5];
    const int*   cols  = (const int*)d_in[6];
    float* out = (float*)d_out;

    // workspace layout (all 4-byte elements; ~32.6 MB total)
    float* support    = (float*)d_ws;                       // N*D
    int*   counts     = (int*)(support + (size_t)N_NODES * D);
    int*   offsets    = counts + N_NODES;                   // N+1
    int*   cursor     = offsets + N_NODES + 1;              // N
    int*   blockSums  = cursor + N_NODES;                   // 256
    int*   sorted_col = blockSums + 256;                    // E
    float* sorted_val = (float*)(sorted_col + N_EDGES);     // E

    const int nScanBlocks = (N_NODES + 255) / 256;          // 196
    const int nEdgeBlocks = (N_EDGES + 255) / 256;          // 3125

    hipMemsetAsync(counts, 0, (size_t)N_NODES * sizeof(int), stream);

    gemm_kernel<<<(N_NODES + 31) / 32, 256, 0, stream>>>(inp, W, support, N_NODES);
    hist_kernel<<<nEdgeBlocks, 256, 0, stream>>>(rows, counts);
    scan1<<<nScanBlocks, 256, 0, stream>>>(counts, offsets, blockSums);
    scan2<<<1, 256, 0, stream>>>(blockSums, nScanBlocks);
    scan3<<<nScanBlocks, 256, 0, stream>>>(offsets, cursor, blockSums);
    scatter_kernel<<<nEdgeBlocks, 256, 0, stream>>>(rows, cols, vals, cursor,
                                                    sorted_col, sorted_val);
    agg_fused<<<(N_NODES * 64 + 255) / 256, 256, 0, stream>>>(
        support, offsets, sorted_col, sorted_val, inp, bias, alpha, out);
}

// Round 4
// 264.877 us; speedup vs baseline: 3.0231x; 1.0398x over previous
//
#include <hip/hip_runtime.h>

#define N_NODES 50000
#define N_EDGES 800000
#define D 128

// ---------------------------------------------------------------------------
// Phase 1: support = inputs @ weight (fp32 vector GEMM, k-tiled, 41KB LDS)
// ---------------------------------------------------------------------------
__global__ __launch_bounds__(256) void gemm_kernel(
    const float* __restrict__ inp, const float* __restrict__ W,
    float* __restrict__ support, int n)
{
    __shared__ float Ws[64][128];   // 32 KB (k-slice of W)
    __shared__ float inT[64][36];   // 9 KB padded transpose
    const int tid = threadIdx.x;
    const int row0 = blockIdx.x * 32;
    const int c0 = (tid & 31) * 4;   // output column
    const int r0 = (tid >> 5) * 4;   // output row within tile
    float acc[4][4] = {};

    for (int kp = 0; kp < 128; kp += 64) {
        const float4* Wg = (const float4*)(W + kp * 128);
        float4* Wl = (float4*)&Ws[0][0];
        #pragma unroll
        for (int i = 0; i < 8; ++i) Wl[tid + 256 * i] = Wg[tid + 256 * i];
        #pragma unroll
        for (int i = 0; i < 2; ++i) {
            int idx = tid + 256 * i;     // 0..511
            int r = idx & 31;
            int c4 = idx >> 5;           // 0..15
            float4 v = make_float4(0.f, 0.f, 0.f, 0.f);
            if (row0 + r < n) v = *(const float4*)&inp[(size_t)(row0 + r) * D + kp + c4 * 4];
            inT[c4 * 4 + 0][r] = v.x;
            inT[c4 * 4 + 1][r] = v.y;
            inT[c4 * 4 + 2][r] = v.z;
            inT[c4 * 4 + 3][r] = v.w;
        }
        __syncthreads();

        #pragma unroll 8
        for (int k = 0; k < 64; ++k) {
            float4 w = *(const float4*)&Ws[k][c0];
            float4 a = *(const float4*)&inT[k][r0];
            acc[0][0] += a.x * w.x; acc[0][1] += a.x * w.y; acc[0][2] += a.x * w.z; acc[0][3] += a.x * w.w;
            acc[1][0] += a.y * w.x; acc[1][1] += a.y * w.y; acc[1][2] += a.y * w.z; acc[1][3] += a.y * w.w;
            acc[2][0] += a.z * w.x; acc[2][1] += a.z * w.y; acc[2][2] += a.z * w.z; acc[2][3] += a.z * w.w;
            acc[3][0] += a.w * w.x; acc[3][1] += a.w * w.y; acc[3][2] += a.w * w.z; acc[3][3] += a.w * w.w;
        }
        __syncthreads();
    }

    #pragma unroll
    for (int i = 0; i < 4; ++i) {
        int r = row0 + r0 + i;
        if (r < n)
            *(float4*)&support[(size_t)r * D + c0] =
                make_float4(acc[i][0], acc[i][1], acc[i][2], acc[i][3]);
    }
}

// ---------------------------------------------------------------------------
// Phase 2a: histogram of destination rows
// ---------------------------------------------------------------------------
__global__ __launch_bounds__(256) void hist_kernel(const int* __restrict__ rows,
                                                   int* __restrict__ counts)
{
    int e = blockIdx.x * 256 + threadIdx.x;
    if (e < N_EDGES) atomicAdd(&counts[rows[e]], 1);
}

// ---------------------------------------------------------------------------
// Phase 2b: single-kernel exclusive scan (ticket-ordered full lookback).
// 196 blocks, all co-resident (1 block/CU); ticket order == arrival order so
// a block only spins on blocks that are already running -> deadlock-free.
// ---------------------------------------------------------------------------
__global__ __launch_bounds__(256) void scan_fused(
    const int* __restrict__ counts, int* __restrict__ offsets,
    int* __restrict__ cursor, int* __restrict__ blockAgg,
    int* __restrict__ flags, int* __restrict__ ticket)
{
    __shared__ int s[256];
    __shared__ int bid_s, prefix_s;
    if (threadIdx.x == 0) bid_s = atomicAdd(ticket, 1);
    __syncthreads();
    const int bid = bid_s;
    const int gid = bid * 256 + threadIdx.x;
    int v = (gid < N_NODES) ? counts[gid] : 0;
    s[threadIdx.x] = v;
    __syncthreads();
    #pragma unroll
    for (int d = 1; d < 256; d <<= 1) {
        int t = (threadIdx.x >= d) ? s[threadIdx.x - d] : 0;
        __syncthreads();
        s[threadIdx.x] += t;
        __syncthreads();
    }
    if (threadIdx.x == 0) {
        __hip_atomic_store(&blockAgg[bid], s[255], __ATOMIC_RELAXED, __HIP_MEMORY_SCOPE_AGENT);
        __hip_atomic_store(&flags[bid], 1, __ATOMIC_RELEASE, __HIP_MEMORY_SCOPE_AGENT);
    }
    if (threadIdx.x < 64) {      // wave 0 does the lookback over predecessors
        int sum = 0;
        for (int j = threadIdx.x; j < bid; j += 64) {
            while (__hip_atomic_load(&flags[j], __ATOMIC_ACQUIRE, __HIP_MEMORY_SCOPE_AGENT) == 0) {}
            sum += __hip_atomic_load(&blockAgg[j], __ATOMIC_RELAXED, __HIP_MEMORY_SCOPE_AGENT);
        }
        #pragma unroll
        for (int d = 1; d < 64; d <<= 1) sum += __shfl_xor(sum, d);
        if (threadIdx.x == 0) prefix_s = sum;
    }
    __syncthreads();
    const int prefix = prefix_s;
    if (gid < N_NODES) {
        int o = prefix + s[threadIdx.x] - v;   // exclusive
        offsets[gid] = o;
        cursor[gid] = o;
    }
    if (gid == 0) offsets[N_NODES] = N_EDGES;
}

// ---------------------------------------------------------------------------
// Phase 2c: scatter edges into CSR order as packed 8B (col, val) pairs --
// one store per edge, bucket entries share cachelines.
// ---------------------------------------------------------------------------
__global__ __launch_bounds__(256) void scatter_kernel(
    const int* __restrict__ rows, const int* __restrict__ cols,
    const float* __restrict__ vals, int* __restrict__ cursor,
    int2* __restrict__ pairs)
{
    int e = blockIdx.x * 256 + threadIdx.x;
    if (e < N_EDGES) {
        int p = atomicAdd(&cursor[rows[e]], 1);
        int2 pk;
        pk.x = cols[e];
        pk.y = __float_as_int(vals[e]);
        pairs[p] = pk;
    }
}

// ---------------------------------------------------------------------------
// Phase 3: per-row gather-reduce (4 gathers in flight) + fused epilogue.
// One wave per destination row; lane owns 2 columns.
// ---------------------------------------------------------------------------
__global__ __launch_bounds__(256) void agg_fused(
    const float* __restrict__ support, const int* __restrict__ offsets,
    const int2* __restrict__ pairs,
    const float* __restrict__ inp, const float* __restrict__ bias,
    const float* __restrict__ alpha, float* __restrict__ out)
{
    const int wave = (blockIdx.x * 256 + threadIdx.x) >> 6;
    const int lane = threadIdx.x & 63;
    if (wave >= N_NODES) return;

    const int start = offsets[wave];
    const int end   = offsets[wave + 1];

    // hoist independent epilogue loads so they overlap the gather loop
    const float2 x = *(const float2*)&inp[(size_t)wave * D + lane * 2];
    const float2 b = *(const float2*)&bias[lane * 2];
    const float a0 = alpha[0], a1 = alpha[1];

    float2 acc = make_float2(0.f, 0.f);
    int e = start;
    for (; e + 4 <= end; e += 4) {           // 4 independent gathers in flight
        int2 p0 = pairs[e], p1 = pairs[e + 1], p2 = pairs[e + 2], p3 = pairs[e + 3];
        float2 s0 = *(const float2*)&support[(size_t)p0.x * D + lane * 2];
        float2 s1 = *(const float2*)&support[(size_t)p1.x * D + lane * 2];
        float2 s2 = *(const float2*)&support[(size_t)p2.x * D + lane * 2];
        float2 s3 = *(const float2*)&support[(size_t)p3.x * D + lane * 2];
        float v0 = __int_as_float(p0.y), v1 = __int_as_float(p1.y);
        float v2 = __int_as_float(p2.y), v3 = __int_as_float(p3.y);
        acc.x += v0 * s0.x + v1 * s1.x + v2 * s2.x + v3 * s3.x;
        acc.y += v0 * s0.y + v1 * s1.y + v2 * s2.y + v3 * s3.y;
    }
    for (; e < end; ++e) {
        int2 p = pairs[e];
        float v = __int_as_float(p.y);
        float2 s = *(const float2*)&support[(size_t)p.x * D + lane * 2];
        acc.x += v * s.x;
        acc.y += v * s.y;
    }

    // softmax gate over alpha[0..1]
    const float m = fmaxf(a0, a1);
    const float e0 = __expf(a0 - m), e1 = __expf(a1 - m);
    const float inv = 1.f / (e0 + e1);
    const float g0 = e0 * inv, g1 = e1 * inv;

    float t0 = acc.x * g0 + x.x * g1 + b.x;
    float t1 = acc.y * g0 + x.y * g1 + b.y;
    float2 o;
    o.x = t0 > 0.f ? t0 : (__expf(t0) - 1.f);
    o.y = t1 > 0.f ? t1 : (__expf(t1) - 1.f);
    *(float2*)&out[(size_t)wave * D + lane * 2] = o;
}

extern "C" void kernel_launch(void* const* d_in, const int* in_sizes, int n_in,
                              void* d_out, int out_size, void* d_ws, size_t ws_size,
                              hipStream_t stream)
{
    const float* inp   = (const float*)d_in[0];
    const float* W     = (const float*)d_in[1];
    const float* bias  = (const float*)d_in[2];
    const float* alpha = (const float*)d_in[3];
    const float* vals  = (const float*)d_in[4];
    const int*   rows  = (const int*)d_in[5];
    const int*   cols  = (const int*)d_in[6];
    float* out = (float*)d_out;

    // workspace layout (ints/floats are 4B; total ~32.6 MB)
    // NOTE: no trailing backslashes in these comments -- a '\' at end of a
    // //-comment is a line continuation and eats the next declaration.
    float* support   = (float*)d_ws;                           // N*D floats
    int*   counts    = (int*)(support + (size_t)N_NODES * D);  // N ints (memset)
    int*   flags     = counts + N_NODES;                       // 256 ints (memset)
    int*   ticket    = flags + 256;                            // 1 int (memset)
    int*   blockAgg  = ticket + 1;                             // 256 ints
    int*   offsets   = blockAgg + 256;                         // N+1 ints
    int*   cursor    = offsets + N_NODES + 1;                  // N ints
    // cumulative int count = 6,400,000+50,000+256+1+256+50,001+50,000 (even)
    int2*  pairs     = (int2*)(cursor + N_NODES);              // E pairs (8B-aligned)

    const int nScanBlocks = (N_NODES + 255) / 256;          // 196
    const int nEdgeBlocks = (N_EDGES + 255) / 256;          // 3125

    // zero counts + flags + ticket in one memset (contiguous)
    (void)hipMemsetAsync(counts, 0, (size_t)(N_NODES + 256 + 1) * sizeof(int), stream);

    gemm_kernel<<<(N_NODES + 31) / 32, 256, 0, stream>>>(inp, W, support, N_NODES);
    hist_kernel<<<nEdgeBlocks, 256, 0, stream>>>(rows, counts);
    scan_fused<<<nScanBlocks, 256, 0, stream>>>(counts, offsets, cursor,
                                                blockAgg, flags, ticket);
    scatter_kernel<<<nEdgeBlocks, 256, 0, stream>>>(rows, cols, vals, cursor, pairs);
    agg_fused<<<(N_NODES * 64 + 255) / 256, 256, 0, stream>>>(
        support, offsets, pairs, inp, bias, alpha, out);
}

// Round 5
// 237.587 us; speedup vs baseline: 3.3703x; 1.1149x over previous
//
#include <hip/hip_runtime.h>

#define N_NODES 50000
#define N_EDGES 800000
#define D 128

typedef __attribute__((ext_vector_type(8))) short bf16x8;
typedef __attribute__((ext_vector_type(4))) float f32x4;

__device__ __forceinline__ short f2bf(float f) {
    unsigned u = __float_as_uint(f);
    unsigned r = u + 0x7FFFu + ((u >> 16) & 1u);   // RNE; inputs finite
    return (short)(r >> 16);
}

// ---------------------------------------------------------------------------
// Phase 1 (merged): blocks [0, nGemmBlocks) do support = inputs @ weight via
// bf16 MFMA (fp32 accum); blocks [nGemmBlocks, ...) do the row histogram.
// GEMM: 64 rows/block, 4 waves; wave w owns rows w*16..w*16+15 x all 128 cols
// = 8 MFMA tiles of 16x16, K swept in 4 chunks of 32. W transposed+converted
// to bf16 in LDS once per block (rows padded to 136 shorts = 272B = 16B*17,
// so every B-frag is one aligned ds_read_b128).
// ---------------------------------------------------------------------------
__global__ __launch_bounds__(256) void gemm_hist_kernel(
    const float* __restrict__ inp, const float* __restrict__ W,
    float* __restrict__ support, const int* __restrict__ rows,
    int* __restrict__ counts, int nGemmBlocks)
{
    if ((int)blockIdx.x >= nGemmBlocks) {
        int e = ((int)blockIdx.x - nGemmBlocks) * 256 + threadIdx.x;
        if (e < N_EDGES) atomicAdd(&counts[rows[e]], 1);
        return;
    }

    __shared__ short Wt[128][136];   // 34 KB: Wt[col][k] bf16
    const int tid = threadIdx.x;

    // stage W: coalesced fp32 read, transpose + bf16 convert into LDS
    #pragma unroll
    for (int i = 0; i < 16; ++i) {
        int lin = i * 1024 + tid * 4;        // linear index into W[k][c]
        int k = lin >> 7;
        int c = lin & 127;
        float4 w = *(const float4*)&W[lin];
        Wt[c + 0][k] = f2bf(w.x);
        Wt[c + 1][k] = f2bf(w.y);
        Wt[c + 2][k] = f2bf(w.z);
        Wt[c + 3][k] = f2bf(w.w);
    }
    __syncthreads();

    const int wid = tid >> 6;
    const int lane = tid & 63;
    const int lr = lane & 15;        // A-row / B-col / D-col index
    const int lg = lane >> 4;        // k-group (0..3)
    const int m0 = (int)blockIdx.x * 64 + wid * 16;

    int arow = m0 + lr;
    if (arow >= N_NODES) arow = 0;   // clamped rows only feed OOB D-rows (not stored)
    const float* aptr = &inp[(size_t)arow * D + lg * 8];

    f32x4 acc[8] = {};

    #pragma unroll
    for (int kc = 0; kc < 4; ++kc) {
        float4 a0 = *(const float4*)(aptr + kc * 32);
        float4 a1 = *(const float4*)(aptr + kc * 32 + 4);
        bf16x8 af;
        af[0] = f2bf(a0.x); af[1] = f2bf(a0.y); af[2] = f2bf(a0.z); af[3] = f2bf(a0.w);
        af[4] = f2bf(a1.x); af[5] = f2bf(a1.y); af[6] = f2bf(a1.z); af[7] = f2bf(a1.w);
        #pragma unroll
        for (int t = 0; t < 8; ++t) {
            const bf16x8 bf = *(const bf16x8*)&Wt[t * 16 + lr][kc * 32 + lg * 8];
            acc[t] = __builtin_amdgcn_mfma_f32_16x16x32_bf16(af, bf, acc[t], 0, 0, 0);
        }
    }

    // D layout: col = lane&15, row = (lane>>4)*4 + reg
    #pragma unroll
    for (int t = 0; t < 8; ++t) {
        #pragma unroll
        for (int r = 0; r < 4; ++r) {
            int orow = m0 + lg * 4 + r;
            if (orow < N_NODES)
                support[(size_t)orow * D + t * 16 + lr] = acc[t][r];
        }
    }
}

// ---------------------------------------------------------------------------
// Phase 2b: single-kernel exclusive scan (ticket-ordered full lookback).
// ---------------------------------------------------------------------------
__global__ __launch_bounds__(256) void scan_fused(
    const int* __restrict__ counts, int* __restrict__ offsets,
    int* __restrict__ cursor, int* __restrict__ blockAgg,
    int* __restrict__ flags, int* __restrict__ ticket)
{
    __shared__ int s[256];
    __shared__ int bid_s, prefix_s;
    if (threadIdx.x == 0) bid_s = atomicAdd(ticket, 1);
    __syncthreads();
    const int bid = bid_s;
    const int gid = bid * 256 + threadIdx.x;
    int v = (gid < N_NODES) ? counts[gid] : 0;
    s[threadIdx.x] = v;
    __syncthreads();
    #pragma unroll
    for (int d = 1; d < 256; d <<= 1) {
        int t = (threadIdx.x >= d) ? s[threadIdx.x - d] : 0;
        __syncthreads();
        s[threadIdx.x] += t;
        __syncthreads();
    }
    if (threadIdx.x == 0) {
        __hip_atomic_store(&blockAgg[bid], s[255], __ATOMIC_RELAXED, __HIP_MEMORY_SCOPE_AGENT);
        __hip_atomic_store(&flags[bid], 1, __ATOMIC_RELEASE, __HIP_MEMORY_SCOPE_AGENT);
    }
    if (threadIdx.x < 64) {
        int sum = 0;
        for (int j = threadIdx.x; j < bid; j += 64) {
            while (__hip_atomic_load(&flags[j], __ATOMIC_ACQUIRE, __HIP_MEMORY_SCOPE_AGENT) == 0) {}
            sum += __hip_atomic_load(&blockAgg[j], __ATOMIC_RELAXED, __HIP_MEMORY_SCOPE_AGENT);
        }
        #pragma unroll
        for (int d = 1; d < 64; d <<= 1) sum += __shfl_xor(sum, d);
        if (threadIdx.x == 0) prefix_s = sum;
    }
    __syncthreads();
    const int prefix = prefix_s;
    if (gid < N_NODES) {
        int o = prefix + s[threadIdx.x] - v;
        offsets[gid] = o;
        cursor[gid] = o;
    }
    if (gid == 0) offsets[N_NODES] = N_EDGES;
}

// ---------------------------------------------------------------------------
// Phase 2c: scatter edges into CSR order as packed 8B (col, val) pairs
// ---------------------------------------------------------------------------
__global__ __launch_bounds__(256) void scatter_kernel(
    const int* __restrict__ rows, const int* __restrict__ cols,
    const float* __restrict__ vals, int* __restrict__ cursor,
    int2* __restrict__ pairs)
{
    int e = blockIdx.x * 256 + threadIdx.x;
    if (e < N_EDGES) {
        int p = atomicAdd(&cursor[rows[e]], 1);
        int2 pk;
        pk.x = cols[e];
        pk.y = __float_as_int(vals[e]);
        pairs[p] = pk;
    }
}

// ---------------------------------------------------------------------------
// Phase 3: per-row gather-reduce + fused epilogue. One wave per row; wave is
// split into two 32-lane halves each owning float4 columns, processing edges
// e+half in parallel (4-deep unroll = 8 x 512B gathers in flight per wave),
// then a cross-half shfl_xor(32) reduce.
// ---------------------------------------------------------------------------
__global__ __launch_bounds__(256) void agg_fused(
    const float* __restrict__ support, const int* __restrict__ offsets,
    const int2* __restrict__ pairs,
    const float* __restrict__ inp, const float* __restrict__ bias,
    const float* __restrict__ alpha, float* __restrict__ out)
{
    const int wv = (blockIdx.x * 256 + threadIdx.x) >> 6;
    const int lane = threadIdx.x & 63;
    if (wv >= N_NODES) return;
    const int half = lane >> 5;
    const int li = lane & 31;

    const int start = offsets[wv];
    const int end   = offsets[wv + 1];

    // hoisted epilogue loads (same in both halves)
    const float4 x = *(const float4*)&inp[(size_t)wv * D + li * 4];
    const float4 b = *(const float4*)&bias[li * 4];
    const float a0 = alpha[0], a1 = alpha[1];

    float4 acc = make_float4(0.f, 0.f, 0.f, 0.f);
    int e = start;
    for (; e + 8 <= end; e += 8) {
        int2 p0 = pairs[e + 0 + half];
        int2 p1 = pairs[e + 2 + half];
        int2 p2 = pairs[e + 4 + half];
        int2 p3 = pairs[e + 6 + half];
        float4 s0 = *(const float4*)&support[(size_t)p0.x * D + li * 4];
        float4 s1 = *(const float4*)&support[(size_t)p1.x * D + li * 4];
        float4 s2 = *(const float4*)&support[(size_t)p2.x * D + li * 4];
        float4 s3 = *(const float4*)&support[(size_t)p3.x * D + li * 4];
        float v0 = __int_as_float(p0.y), v1 = __int_as_float(p1.y);
        float v2 = __int_as_float(p2.y), v3 = __int_as_float(p3.y);
        acc.x += v0 * s0.x + v1 * s1.x + v2 * s2.x + v3 * s3.x;
        acc.y += v0 * s0.y + v1 * s1.y + v2 * s2.y + v3 * s3.y;
        acc.z += v0 * s0.z + v1 * s1.z + v2 * s2.z + v3 * s3.z;
        acc.w += v0 * s0.w + v1 * s1.w + v2 * s2.w + v3 * s3.w;
    }
    for (; e < end; e += 2) {
        int idx = e + half;
        int2 p = (idx < end) ? pairs[idx] : make_int2(0, 0);   // v = 0.0f when invalid
        float v = __int_as_float(p.y);
        float4 s = *(const float4*)&support[(size_t)p.x * D + li * 4];
        acc.x += v * s.x;
        acc.y += v * s.y;
        acc.z += v * s.z;
        acc.w += v * s.w;
    }

    // cross-half reduce: both halves end with the full row sum
    acc.x += __shfl_xor(acc.x, 32);
    acc.y += __shfl_xor(acc.y, 32);
    acc.z += __shfl_xor(acc.z, 32);
    acc.w += __shfl_xor(acc.w, 32);

    // softmax gate
    const float m = fmaxf(a0, a1);
    const float e0 = __expf(a0 - m), e1 = __expf(a1 - m);
    const float inv = 1.f / (e0 + e1);
    const float g0 = e0 * inv, g1 = e1 * inv;

    float t0 = acc.x * g0 + x.x * g1 + b.x;
    float t1 = acc.y * g0 + x.y * g1 + b.y;
    float t2 = acc.z * g0 + x.z * g1 + b.z;
    float t3 = acc.w * g0 + x.w * g1 + b.w;
    float r0 = t0 > 0.f ? t0 : (__expf(t0) - 1.f);
    float r1 = t1 > 0.f ? t1 : (__expf(t1) - 1.f);
    float r2 = t2 > 0.f ? t2 : (__expf(t2) - 1.f);
    float r3 = t3 > 0.f ? t3 : (__expf(t3) - 1.f);

    // half 0 stores the low float2, half 1 the high float2 (fully coalesced)
    float2 o = (half == 0) ? make_float2(r0, r1) : make_float2(r2, r3);
    *(float2*)&out[(size_t)wv * D + li * 4 + half * 2] = o;
}

extern "C" void kernel_launch(void* const* d_in, const int* in_sizes, int n_in,
                              void* d_out, int out_size, void* d_ws, size_t ws_size,
                              hipStream_t stream)
{
    const float* inp   = (const float*)d_in[0];
    const float* W     = (const float*)d_in[1];
    const float* bias  = (const float*)d_in[2];
    const float* alpha = (const float*)d_in[3];
    const float* vals  = (const float*)d_in[4];
    const int*   rows  = (const int*)d_in[5];
    const int*   cols  = (const int*)d_in[6];
    float* out = (float*)d_out;

    // workspace layout (all 4B elements; ~32.6 MB total; no trailing
    // backslashes in comments -- they splice the next line)
    float* support   = (float*)d_ws;                           // N*D floats
    int*   counts    = (int*)(support + (size_t)N_NODES * D);  // N ints (memset)
    int*   flags     = counts + N_NODES;                       // 256 ints (memset)
    int*   ticket    = flags + 256;                            // 1 int (memset)
    int*   blockAgg  = ticket + 1;                             // 256 ints
    int*   offsets   = blockAgg + 256;                         // N+1 ints
    int*   cursor    = offsets + N_NODES + 1;                  // N ints
    int2*  pairs     = (int2*)(cursor + N_NODES);              // E pairs (8B-aligned)

    const int nGemmBlocks = (N_NODES + 63) / 64;            // 782
    const int nEdgeBlocks = (N_EDGES + 255) / 256;          // 3125
    const int nScanBlocks = (N_NODES + 255) / 256;          // 196

    (void)hipMemsetAsync(counts, 0, (size_t)(N_NODES + 256 + 1) * sizeof(int), stream);

    gemm_hist_kernel<<<nGemmBlocks + nEdgeBlocks, 256, 0, stream>>>(
        inp, W, support, rows, counts, nGemmBlocks);
    scan_fused<<<nScanBlocks, 256, 0, stream>>>(counts, offsets, cursor,
                                                blockAgg, flags, ticket);
    scatter_kernel<<<nEdgeBlocks, 256, 0, stream>>>(rows, cols, vals, cursor, pairs);
    agg_fused<<<(N_NODES * 64 + 255) / 256, 256, 0, stream>>>(
        support, offsets, pairs, inp, bias, alpha, out);
}